// Round 6
// baseline (234.747 us; speedup 1.0000x reference)
//
#include <hip/hip_runtime.h>
#include <math.h>

// Problem constants (fixed by reference setup_inputs)
#define S      2048
#define DK     64
#define NBH    32            // B*H
#define QROWS  64            // q rows per block (4 waves x 16)
#define NQT    (S / QROWS)   // 32 q-tiles per bh
#define NKT    (S / 64)      // 32 k-chunks of 64 rows
#define NBLK   (NQT * NBH)   // 1024 blocks
#define NTHR   256

typedef __bf16 bf16x8 __attribute__((ext_vector_type(8)));
typedef float  f32x4  __attribute__((ext_vector_type(4)));
typedef float  f32x8  __attribute__((ext_vector_type(8)));

#if __has_builtin(__builtin_amdgcn_exp2f)
#define EXP2F(x) __builtin_amdgcn_exp2f(x)
#else
#define EXP2F(x) exp2f(x)
#endif

__device__ __forceinline__ float gelu_exact(float x) {
    return 0.5f * x * (1.0f + erff(x * 0.70710678118654752f));
}

// ---------------------------------------------------------------------------
// Fused attention-stats + MLP head, v6.
// Post-mortems r1-r5: bf16-LDS staging is right (r1=102us best); failures
// were (a) 1-phase prefetch slack, (b) VGPR balloons (r3/r4: 256 -> 2
// waves/SIMD).  v6 = r3's triple-buffer ring with BOTH fixed:
//  * __launch_bounds__(256,4): VGPR cap 128 -> 4 blocks/CU (LDS 27.6KB x4)
//    = 16 waves/CU, 4 independent barrier domains per CU.
//  * TWO parity-named register sets (chunk c -> set c&1; static slots, no
//    runtime-indexed arrays): loads issued at chunk c are LDS-written at
//    chunk c+2 -> implicit counted vmcnt(4) at the write, never drained to
//    0, with ~2 compute phases (~700 cyc) of slack.
//  * ONE raw s_barrier + lgkmcnt(0) per chunk.  Triple ring is race-free:
//    the writer of ring slot X and the previous reader of X are 3 chunks
//    apart (>=1 barrier strictly between, see comments).
// Grid (32 bh, 32 qt) bh-major: XCD-pinned K (r3/r4: FETCH 74->16.5 MB).
// Per chunk each wave: 16(q)x64(k) strip via 8x mfma_f32_16x16x32_bf16 and
// per-row no-max softmax stats in the log2 domain (Q pre-scaled by
// (1/8)*log2e; m,Z=sum 2^s',Z2=sum 2^2s',sm=sum s'; sum/max restored by
// *ln2; Z/Z2/var domain-invariant; |s'|<~9 so 2^s' never overflows).
// Last block (atomic counter) runs the 3->64->64->1 GELU MLP head.
// ---------------------------------------------------------------------------
__global__ __launch_bounds__(NTHR, 4) void fused_attn_stats_mlp(
    const float* __restrict__ Q, const float* __restrict__ K,
    const float* __restrict__ W1, const float* __restrict__ b1,
    const float* __restrict__ W2, const float* __restrict__ b2,
    const float* __restrict__ W3, const float* __restrict__ b3,
    float* __restrict__ ws, float* __restrict__ out)
{
    __shared__ __align__(16) __bf16 Ks[3][64][72];   // 27.6 KB triple ring
    __shared__ float red[3];
    __shared__ int lastF;

    const int t    = threadIdx.x;
    const int lane = t & 63;
    const int w    = t >> 6;        // wave 0..3 -> q rows [16w,16w+16)
    const int lrow = lane & 15;     // fragment row index
    const int lq   = lane >> 4;     // quad: d = lq*8 + j
    const int bh   = blockIdx.x;
    const int qt   = blockIdx.y;

    // staging: thread t owns row t>>2, float cols [(t&3)*16, +16) of a chunk
    const float* gK = K + (size_t)bh * S * DK + (size_t)(t >> 2) * DK + (t & 3) * 16;

    // two parity-named in-flight register sets (chunk parity -> set)
    f32x4 p0a, p0b, p0c, p0d;       // even chunks
    f32x4 p1a, p1b, p1c, p1d;       // odd chunks

#define ISSUE0(c) { const float* _p = gK + (size_t)(c) * 4096;       \
        p0a = *(const f32x4*)(_p);      p0b = *(const f32x4*)(_p + 4);  \
        p0c = *(const f32x4*)(_p + 8);  p0d = *(const f32x4*)(_p + 12); }
#define ISSUE1(c) { const float* _p = gK + (size_t)(c) * 4096;       \
        p1a = *(const f32x4*)(_p);      p1b = *(const f32x4*)(_p + 4);  \
        p1c = *(const f32x4*)(_p + 8);  p1d = *(const f32x4*)(_p + 12); }

    // convert 16 floats -> bf16 and store 32 B (2x ds_write_b128)
#define WRITE0(dst) {                                                 \
        f32x8 _lo = __builtin_shufflevector(p0a, p0b, 0,1,2,3,4,5,6,7); \
        f32x8 _hi = __builtin_shufflevector(p0c, p0d, 0,1,2,3,4,5,6,7); \
        *(bf16x8*)&dst[t >> 2][(t & 3) * 16]     = __builtin_convertvector(_lo, bf16x8); \
        *(bf16x8*)&dst[t >> 2][(t & 3) * 16 + 8] = __builtin_convertvector(_hi, bf16x8); }
#define WRITE1(dst) {                                                 \
        f32x8 _lo = __builtin_shufflevector(p1a, p1b, 0,1,2,3,4,5,6,7); \
        f32x8 _hi = __builtin_shufflevector(p1c, p1d, 0,1,2,3,4,5,6,7); \
        *(bf16x8*)&dst[t >> 2][(t & 3) * 16]     = __builtin_convertvector(_lo, bf16x8); \
        *(bf16x8*)&dst[t >> 2][(t & 3) * 16 + 8] = __builtin_convertvector(_hi, bf16x8); }

#define PIPE_BAR() {                                                  \
        asm volatile("s_waitcnt lgkmcnt(0)" ::: "memory");            \
        __builtin_amdgcn_s_barrier();                                 \
        asm volatile("" ::: "memory"); }

#define COMPUTE(src) {                                                \
        _Pragma("unroll")                                             \
        for (int ct = 0; ct < 4; ++ct) {                              \
            const bf16x8 _blo = *(const bf16x8*)&src[ct * 16 + lrow][lq * 8];      \
            const bf16x8 _bhi = *(const bf16x8*)&src[ct * 16 + lrow][32 + lq * 8]; \
            f32x4 _acc = {0.f, 0.f, 0.f, 0.f};                        \
            _acc = __builtin_amdgcn_mfma_f32_16x16x32_bf16(a_lo, _blo, _acc, 0, 0, 0); \
            _acc = __builtin_amdgcn_mfma_f32_16x16x32_bf16(a_hi, _bhi, _acc, 0, 0, 0); \
            _Pragma("unroll")                                         \
            for (int i = 0; i < 4; ++i) {                             \
                const float s = _acc[i];                              \
                const float p = EXP2F(s);                             \
                m[i]  = fmaxf(m[i], s);                               \
                Zs[i] += p;                                           \
                Z2[i]  = fmaf(p, p, Z2[i]);                           \
                sm[i] += s;                                           \
            }                                                         \
        } }

    // ---- prologue: chunks 0,1 in flight; A-fragments; chunk0 -> ring0 ----
    ISSUE0(0);
    ISSUE1(1);

    const float* qrow = Q + ((size_t)bh * S + (size_t)qt * QROWS + w * 16 + lrow) * DK;
    const float SC = 0.18033688011112042592f;   // (1/sqrt(64)) * log2(e)
    f32x8 q0 = *(const f32x8*)(qrow + lq * 8);
    f32x8 q1 = *(const f32x8*)(qrow + 32 + lq * 8);
    const bf16x8 a_lo = __builtin_convertvector(q0 * SC, bf16x8);
    const bf16x8 a_hi = __builtin_convertvector(q1 * SC, bf16x8);

    if (t < 3) red[t] = 0.0f;

    typedef __bf16 (*buf_t)[72];
    buf_t rd = (buf_t)&Ks[0][0][0];
    buf_t wr = (buf_t)&Ks[1][0][0];
    buf_t ex = (buf_t)&Ks[2][0][0];

    WRITE0(rd);                     // chunk 0 -> ring0 (waits only its own loads)
    ISSUE0(2);                      // chunk 2 in flight
    __syncthreads();                // once: ring0 + red[] visible

    float m[4], Zs[4], Z2[4], sm[4];
#pragma unroll
    for (int i = 0; i < 4; ++i) { m[i] = -INFINITY; Zs[i] = 0.f; Z2[i] = 0.f; sm[i] = 0.f; }

    // ---- main loop: 2 chunks/iter, ONE barrier/chunk, 2-phase load slack --
    // Race-freedom: WRITE at chunk c+1 targets the ring slot last READ at
    // chunk c-2; the reader passed barrier c-1 (after its read), and this
    // WRITE is issued after barrier c-1 in program order -> ordered.
    for (int c = 0; c < NKT; c += 2) {
        // chunk c (even): write chunk c+1 (set1), refill set1 with c+3
        WRITE1(wr);                                   // vmcnt wait: ~2 phases old
        if (c + 3 < NKT) ISSUE1(c + 3);
        PIPE_BAR();
        COMPUTE(rd);                                  // chunk c
        { buf_t tmp = rd; rd = wr; wr = ex; ex = tmp; }

        // chunk c+1 (odd): write chunk c+2 (set0), refill set0 with c+4
        if (c + 2 < NKT) { WRITE0(wr); }
        if (c + 4 < NKT) ISSUE0(c + 4);
        PIPE_BAR();
        COMPUTE(rd);                                  // chunk c+1
        { buf_t tmp = rd; rd = wr; wr = ex; ex = tmp; }
    }

    // ---- reduce across the 16 column-lanes sharing each q-row ----
#pragma unroll
    for (int off = 1; off < 16; off <<= 1) {
#pragma unroll
        for (int i = 0; i < 4; ++i) {
            m[i]   = fmaxf(m[i], __shfl_xor(m[i], off, 64));
            Zs[i] += __shfl_xor(Zs[i], off, 64);
            Z2[i] += __shfl_xor(Z2[i], off, 64);
            sm[i] += __shfl_xor(sm[i], off, 64);
        }
    }
    if (lrow == 0) {
        const float LN2 = 0.69314718055994530942f;
        float psum = 0.f, pmax = 0.f, pvar = 0.f;
#pragma unroll
        for (int i = 0; i < 4; ++i) {
            psum += sm[i];
            pmax += m[i];
            const float iz = 1.0f / Zs[i];
            // var(probs, ddof=1) = (Z2/Z^2 - 1/n)/(n-1); scale-invariant
            pvar += (Z2[i] * iz * iz - (1.0f / 2048.0f)) * (1.0f / 2047.0f);
        }
        atomicAdd(&red[0], psum * LN2);     // back to natural-log domain
        atomicAdd(&red[1], pmax * LN2);
        atomicAdd(&red[2], pvar);
    }
    __syncthreads();
    if (t == 0) {
        atomicAdd(&ws[bh * 3 + 0], red[0]);
        atomicAdd(&ws[bh * 3 + 1], red[1]);
        atomicAdd(&ws[bh * 3 + 2], red[2]);
        __threadfence();
        const int old = atomicAdd((int*)(ws + 96), 1);
        lastF = (old == NBLK - 1);
    }
    __syncthreads();
    if (!lastF) return;

    // =========================== MLP head (last block) ======================
    float* H1    = (float*)&Ks[0][0][0];   // 32*65 floats
    float* featL = H1 + 32 * 65;           // 96 floats
    float* logtL = featL + 96;             // 32 floats   (8832 B < 27 KB)

    if (t < 96)               featL[t] = atomicAdd(&ws[t], 0.0f); // coherent read
    if (t >= 96 && t < 128)   logtL[t - 96] = 0.0f;
    __syncthreads();

    if (t < 64) {
        const float w1a = W1[t], w1b = W1[64 + t], w1c = W1[128 + t], bb1 = b1[t];
        for (int b = 0; b < 32; ++b) {
            const float f0 = featL[b * 3 + 0] * (1.0f / ((float)S * (float)S));
            const float f1 = featL[b * 3 + 1] * (1.0f / (float)S);
            const float f2 = featL[b * 3 + 2] * (1.0f / (float)S);
            H1[b * 65 + t] = gelu_exact(f0 * w1a + f1 * w1b + f2 * w1c + bb1);
        }
    }
    __syncthreads();
    {
        // 256 threads: 8 threads per bh, 8 hidden-2 units each
        const int b = t >> 3, jb = (t & 7) * 8;
        float acc[8];
#pragma unroll
        for (int u = 0; u < 8; ++u) acc[u] = 0.0f;
        for (int k = 0; k < 64; ++k) {
            const float hk = H1[b * 65 + k];
            const float4 wa = *(const float4*)&W2[k * 64 + jb];
            const float4 wb = *(const float4*)&W2[k * 64 + jb + 4];
            acc[0] += hk * wa.x; acc[1] += hk * wa.y;
            acc[2] += hk * wa.z; acc[3] += hk * wa.w;
            acc[4] += hk * wb.x; acc[5] += hk * wb.y;
            acc[6] += hk * wb.z; acc[7] += hk * wb.w;
        }
        float part = 0.0f;
#pragma unroll
        for (int u = 0; u < 8; ++u)
            part += gelu_exact(acc[u] + b2[jb + u]) * W3[jb + u];
        atomicAdd(&logtL[b], part);
    }
    __syncthreads();
    if (t < 32) {
        float lt = logtL[t] + b3[0];
        lt = fminf(fmaxf(lt, -2.3025850929940457f), 2.3025850929940457f);
        out[t] = expf(lt);
    }
}

// ---------------------------------------------------------------------------
extern "C" void kernel_launch(void* const* d_in, const int* in_sizes, int n_in,
                              void* d_out, int out_size, void* d_ws, size_t ws_size,
                              hipStream_t stream)
{
    const float* Q  = (const float*)d_in[0];
    const float* K  = (const float*)d_in[1];
    const float* W1 = (const float*)d_in[2];
    const float* b1 = (const float*)d_in[3];
    const float* W2 = (const float*)d_in[4];
    const float* b2 = (const float*)d_in[5];
    const float* W3 = (const float*)d_in[6];
    const float* b3 = (const float*)d_in[7];
    float* out = (float*)d_out;
    float* ws  = (float*)d_ws;

    // zero the 96 stat accumulators + the int block counter at ws[96]
    hipMemsetAsync(ws, 0, 512, stream);

    dim3 grid(NBH, NQT);   // bh fastest -> each bh's K pinned to one XCD L2
    fused_attn_stats_mlp<<<grid, NTHR, 0, stream>>>(Q, K, W1, b1, W2, b2, W3, b3, ws, out);
}

// Round 7
// 166.148 us; speedup vs baseline: 1.4129x; 1.4129x over previous
//
#include <hip/hip_runtime.h>
#include <math.h>

// Problem constants (fixed by reference setup_inputs)
#define S      2048
#define DK     64
#define NBH    32            // B*H
#define QBLK   128           // q rows per block (8 waves x 16)
#define NQB    (S / QBLK)    // 16 q-tiles per bh
#define NBLK   (NBH * NQB)   // 512 blocks
#define NTHR   512
#define KPH    512           // K rows staged per phase (64 KB bf16)
#define NPH    (S / KPH)     // 4 staging phases
#define NST    (KPH / 16)    // 32 MFMA steps per phase

typedef __bf16 bf16x4 __attribute__((ext_vector_type(4)));
typedef __bf16 bf16x8 __attribute__((ext_vector_type(8)));
typedef float  f32x4  __attribute__((ext_vector_type(4)));
typedef float  f32x8  __attribute__((ext_vector_type(8)));

#if __has_builtin(__builtin_amdgcn_exp2f)
#define EXP2F(x) __builtin_amdgcn_exp2f(x)
#else
#define EXP2F(x) exp2f(x)
#endif

__device__ __forceinline__ float gelu_exact(float x) {
    return 0.5f * x * (1.0f + erff(x * 0.70710678118654752f));
}

// ---------------------------------------------------------------------------
// Fused attention-stats + MLP head, v7: STAGE-ONCE / COMPUTE-LONG.
// Cross-round fact (r1-r6): VALU-busy time is ~21 us in EVERY variant; all
// structures that re-ingest K per 64-row chunk stall 80-90% regardless of
// buffering depth.  v7 inverts the loop: each block stages a 512-row K
// phase (64 KB bf16, XOR-swizzled) into LDS ONCE, then runs 32 barrier-free
// MFMA+stats steps against it; 4 phases cover k=0..2047.  Barriers: 9 per
// block (vs 33).  Grid (32 bh, 16 qt) bh-major (XCD-pinned K; r3: FETCH
// 74->16.5 MB).  2 blocks/CU (128 KB LDS) x 8 waves = 16 waves/CU; waves
// are fully independent inside each ~9k-cycle compute phase, and the other
// block's compute covers this block's staging latency.
// T2 swizzle: 16B group c8 of row r stored at c8^(r&7) -> B-fragment
// ds_read_b128 is 2-way (free, m136) instead of 16-way.
// Stats per wave: 16 q-rows, per-row no-max softmax stats in the log2
// domain (Q pre-scaled by (1/8)*log2e): m=max s', Z=sum 2^s', Z2=sum 2^2s',
// sm=sum s'; sum/max restored by *ln2 at the end; Z/Z2/var are
// domain-invariant; |s'| <~ 9 so 2^s' never overflows.
// red/lastF/head scratch ALIAS the K buffer after the final compute
// barrier (keeps static LDS at exactly 64 KB).
// Last block (atomic counter) runs the 3->64->64->1 GELU MLP head.
// ---------------------------------------------------------------------------
__global__ __launch_bounds__(NTHR) void fused_attn_stats_mlp(
    const float* __restrict__ Q, const float* __restrict__ K,
    const float* __restrict__ W1, const float* __restrict__ b1,
    const float* __restrict__ W2, const float* __restrict__ b2,
    const float* __restrict__ W3, const float* __restrict__ b3,
    float* __restrict__ ws, float* __restrict__ out)
{
    __shared__ __align__(16) unsigned char smem[64 * 1024];  // Ks[512][64] bf16

    const int t    = threadIdx.x;
    const int lane = t & 63;
    const int w    = t >> 6;        // wave 0..7 -> q rows [16w, 16w+16)
    const int lrow = lane & 15;     // fragment row index
    const int lq   = lane >> 4;     // quad: d = lq*8 + j
    const int bh   = blockIdx.x;
    const int qb   = blockIdx.y;

    // ---- A fragments (16 q-rows/wave), scaled by (1/8)*log2(e) ----
    const float SC = 0.18033688011112042592f;
    const float* qrow = Q + ((size_t)bh * S + (size_t)qb * QBLK + w * 16 + lrow) * DK;
    f32x8 q0 = *(const f32x8*)(qrow + lq * 8);
    f32x8 q1 = *(const f32x8*)(qrow + 32 + lq * 8);
    const bf16x8 a_lo = __builtin_convertvector(q0 * SC, bf16x8);
    const bf16x8 a_hi = __builtin_convertvector(q1 * SC, bf16x8);

    float m[4], Zs[4], Z2[4], sm[4];
#pragma unroll
    for (int i = 0; i < 4; ++i) { m[i] = -INFINITY; Zs[i] = 0.f; Z2[i] = 0.f; sm[i] = 0.f; }

    char* KsB = (char*)smem;
    const float* Kb = K + (size_t)bh * S * DK;

    // swizzled store of one float4 (as bf16x4) at (row, c4) of the phase tile
#define STG(ui, I) {                                                       \
        const int _n = (I) * 512 + t;          /* float4 index, 0..8191 */ \
        const int _r = _n >> 4;                /* row 0..511            */ \
        const int _c4 = _n & 15;                                           \
        const int _b = _r * 128 + ((((_c4 >> 1) ^ (_r & 7))) << 4) + ((_c4 & 1) << 3); \
        *(bf16x4*)(KsB + _b) = __builtin_convertvector(ui, bf16x4); }

    for (int p = 0; p < NPH; ++p) {
        if (p) __syncthreads();                 // all reads of prev phase done
        // ---- stage 512 K rows (coalesced dwordx4, two 8-load batches) ----
        {
            const float* gp = Kb + (size_t)p * (KPH * DK) + (size_t)t * 4;
            f32x4 u0, u1, u2, u3, u4, u5, u6, u7;
            u0 = *(const f32x4*)(gp);            u1 = *(const f32x4*)(gp + 2048);
            u2 = *(const f32x4*)(gp + 4096);     u3 = *(const f32x4*)(gp + 6144);
            u4 = *(const f32x4*)(gp + 8192);     u5 = *(const f32x4*)(gp + 10240);
            u6 = *(const f32x4*)(gp + 12288);    u7 = *(const f32x4*)(gp + 14336);
            STG(u0, 0) STG(u1, 1) STG(u2, 2) STG(u3, 3)
            STG(u4, 4) STG(u5, 5) STG(u6, 6) STG(u7, 7)
            u0 = *(const f32x4*)(gp + 16384);    u1 = *(const f32x4*)(gp + 18432);
            u2 = *(const f32x4*)(gp + 20480);    u3 = *(const f32x4*)(gp + 22528);
            u4 = *(const f32x4*)(gp + 24576);    u5 = *(const f32x4*)(gp + 26624);
            u6 = *(const f32x4*)(gp + 28672);    u7 = *(const f32x4*)(gp + 30720);
            STG(u0, 8)  STG(u1, 9)  STG(u2, 10) STG(u3, 11)
            STG(u4, 12) STG(u5, 13) STG(u6, 14) STG(u7, 15)
        }
        __syncthreads();                        // phase tile visible

        // ---- 32 barrier-free MFMA+stats steps against this phase ----
        // swizzle xor term is j-invariant: (j*16+lrow)&7 == lrow&7
        const int obase = lrow * 128 + ((lq ^ (lrow & 7)) << 4);
#pragma unroll 4
        for (int j = 0; j < NST; ++j) {
            const int off = j * 2048 + obase;
            const bf16x8 b_lo = *(const bf16x8*)(KsB + off);
            const bf16x8 b_hi = *(const bf16x8*)(KsB + (off ^ 64));
            f32x4 acc = {0.f, 0.f, 0.f, 0.f};
            acc = __builtin_amdgcn_mfma_f32_16x16x32_bf16(a_lo, b_lo, acc, 0, 0, 0);
            acc = __builtin_amdgcn_mfma_f32_16x16x32_bf16(a_hi, b_hi, acc, 0, 0, 0);
#pragma unroll
            for (int i = 0; i < 4; ++i) {
                const float s = acc[i];          // s' = score * log2e
                const float pp = EXP2F(s);       // = e^score exactly
                m[i]  = fmaxf(m[i], s);
                Zs[i] += pp;
                Z2[i]  = fmaf(pp, pp, Z2[i]);
                sm[i] += s;
            }
        }
    }
    __syncthreads();                            // compute done; LDS reusable

    int*   lastF = (int*)smem;
    float* red   = (float*)(smem + 16);
    if (t < 3) red[t] = 0.0f;
    __syncthreads();

    // ---- reduce across the 16 column-lanes sharing each q-row ----
#pragma unroll
    for (int off = 1; off < 16; off <<= 1) {
#pragma unroll
        for (int i = 0; i < 4; ++i) {
            m[i]   = fmaxf(m[i], __shfl_xor(m[i], off, 64));
            Zs[i] += __shfl_xor(Zs[i], off, 64);
            Z2[i] += __shfl_xor(Z2[i], off, 64);
            sm[i] += __shfl_xor(sm[i], off, 64);
        }
    }
    if (lrow == 0) {
        const float LN2 = 0.69314718055994530942f;
        float psum = 0.f, pmax = 0.f, pvar = 0.f;
#pragma unroll
        for (int i = 0; i < 4; ++i) {
            psum += sm[i];
            pmax += m[i];
            const float iz = 1.0f / Zs[i];
            // var(probs, ddof=1) = (Z2/Z^2 - 1/n)/(n-1); scale-invariant
            pvar += (Z2[i] * iz * iz - (1.0f / 2048.0f)) * (1.0f / 2047.0f);
        }
        atomicAdd(&red[0], psum * LN2);         // back to natural-log domain
        atomicAdd(&red[1], pmax * LN2);
        atomicAdd(&red[2], pvar);
    }
    __syncthreads();
    if (t == 0) {
        atomicAdd(&ws[bh * 3 + 0], red[0]);
        atomicAdd(&ws[bh * 3 + 1], red[1]);
        atomicAdd(&ws[bh * 3 + 2], red[2]);
        __threadfence();
        const int old = atomicAdd((int*)(ws + 96), 1);
        *lastF = (old == NBLK - 1);
    }
    __syncthreads();
    if (!*lastF) return;

    // =========================== MLP head (last block) ======================
    float* H1    = (float*)(smem + 64);     // 32*65 floats
    float* featL = H1 + 32 * 65;            // 96 floats
    float* logtL = featL + 96;              // 32 floats

    if (t < 96)               featL[t] = atomicAdd(&ws[t], 0.0f); // coherent read
    if (t >= 96 && t < 128)   logtL[t - 96] = 0.0f;
    __syncthreads();

    if (t < 64) {
        const float w1a = W1[t], w1b = W1[64 + t], w1c = W1[128 + t], bb1 = b1[t];
        for (int b = 0; b < 32; ++b) {
            const float f0 = featL[b * 3 + 0] * (1.0f / ((float)S * (float)S));
            const float f1 = featL[b * 3 + 1] * (1.0f / (float)S);
            const float f2 = featL[b * 3 + 2] * (1.0f / (float)S);
            H1[b * 65 + t] = gelu_exact(f0 * w1a + f1 * w1b + f2 * w1c + bb1);
        }
    }
    __syncthreads();
    {
        // 512 threads: 16 threads per bh, 4 hidden-2 units each
        const int b = t >> 4, jb = (t & 15) * 4;
        float a0 = 0.f, a1 = 0.f, a2 = 0.f, a3 = 0.f;
        for (int k = 0; k < 64; ++k) {
            const float hk = H1[b * 65 + k];
            const float4 wa = *(const float4*)&W2[k * 64 + jb];
            a0 += hk * wa.x; a1 += hk * wa.y; a2 += hk * wa.z; a3 += hk * wa.w;
        }
        const float part = gelu_exact(a0 + b2[jb + 0]) * W3[jb + 0]
                         + gelu_exact(a1 + b2[jb + 1]) * W3[jb + 1]
                         + gelu_exact(a2 + b2[jb + 2]) * W3[jb + 2]
                         + gelu_exact(a3 + b2[jb + 3]) * W3[jb + 3];
        atomicAdd(&logtL[b], part);
    }
    __syncthreads();
    if (t < 32) {
        float lt = logtL[t] + b3[0];
        lt = fminf(fmaxf(lt, -2.3025850929940457f), 2.3025850929940457f);
        out[t] = expf(lt);
    }
}

// ---------------------------------------------------------------------------
extern "C" void kernel_launch(void* const* d_in, const int* in_sizes, int n_in,
                              void* d_out, int out_size, void* d_ws, size_t ws_size,
                              hipStream_t stream)
{
    const float* Q  = (const float*)d_in[0];
    const float* K  = (const float*)d_in[1];
    const float* W1 = (const float*)d_in[2];
    const float* b1 = (const float*)d_in[3];
    const float* W2 = (const float*)d_in[4];
    const float* b2 = (const float*)d_in[5];
    const float* W3 = (const float*)d_in[6];
    const float* b3 = (const float*)d_in[7];
    float* out = (float*)d_out;
    float* ws  = (float*)d_ws;

    // zero the 96 stat accumulators + the int block counter at ws[96]
    hipMemsetAsync(ws, 0, 512, stream);

    dim3 grid(NBH, NQB);   // bh fastest -> each bh's K pinned to one XCD L2
    fused_attn_stats_mlp<<<grid, NTHR, 0, stream>>>(Q, K, W1, b1, W2, b2, W3, b3, ws, out);
}

// Round 8
// 157.150 us; speedup vs baseline: 1.4938x; 1.0573x over previous
//
#include <hip/hip_runtime.h>
#include <math.h>

// Problem constants (fixed by reference setup_inputs)
#define S      2048
#define DK     64
#define NBH    32            // B*H
#define QW     32            // q rows per WAVE (two A-fragment pairs)
#define QBLK   256           // q rows per block (8 waves x 32)
#define NQB    (S / QBLK)    // 8 q-tiles per bh
#define NBLK   (NBH * NQB)   // 256 blocks = 1 per CU (single generation)
#define NTHR   512
#define KPH    256           // K rows per phase (32 KB bf16)
#define NPH    (S / KPH)     // 8 phases
#define NST    (KPH / 16)    // 16 MFMA steps per phase

typedef __bf16 bf16x8 __attribute__((ext_vector_type(8)));
typedef float  f32x4  __attribute__((ext_vector_type(4)));
typedef float  f32x8  __attribute__((ext_vector_type(8)));

#if __has_builtin(__builtin_amdgcn_exp2f)
#define EXP2F(x) __builtin_amdgcn_exp2f(x)
#else
#define EXP2F(x) exp2f(x)
#endif

__device__ __forceinline__ float gelu_exact(float x) {
    return 0.5f * x * (1.0f + erff(x * 0.70710678118654752f));
}

// ---------------------------------------------------------------------------
// Fused attention-stats + MLP head, v8: FAT WAVES + stage-once phases.
// Ledger r1-r7: every structure stalls ~80% with VALU-busy ~20 us; staging
// style / barrier count / buffer depth are all neutral -> the wall is
// per-step ILP: ~140 issue cycles vs ~300-cycle dep chain (ds_read -> 2
// chained MFMA -> hazard -> exp).  v8 raises issue density per step:
//  * 32 q-rows/WAVE (two A-frag pairs): each ds_read pair feeds 4 MFMA +
//    8 exp + ~32 stat-VALU (~280 issue cyc/step ~= crit path) and 8
//    independent stat chains bridge the MFMA->VALU hazard.
//  * Grid (32 bh, 8 qt) = 256 blocks = 1/CU -> single generation; bh-major
//    keeps XCD-pinned K (FETCH 74->16.5 MB since r3).
//  * K staged phase-wise: 256 rows -> 32 KB bf16, double-buffered (64 KB),
//    T2 XOR-swizzle (r7: conflicts = 0).  T14 split: loads for phase p+1
//    issue at the START of phase p's 16-step compute (~2.5k cyc slack),
//    cvt+ds_write at its end, ONE raw s_barrier per phase (8 total);
//    vmcnt never drained at a barrier.
// Stats in the log2 domain (Q pre-scaled by (1/8)*log2e): per q-row
// m=max s', Z=sum 2^s', Z2=sum 2^2s', sm=sum s'; sum/max restored by *ln2;
// Z/Z2/var domain-invariant; |s'| <~ 9 so 2^s' never overflows.
// red/lastF/head scratch alias the K buffer after the final barrier.
// Last block (atomic counter) runs the 3->64->64->1 GELU MLP head.
// ---------------------------------------------------------------------------
__global__ __launch_bounds__(NTHR) void fused_attn_stats_mlp(
    const float* __restrict__ Q, const float* __restrict__ K,
    const float* __restrict__ W1, const float* __restrict__ b1,
    const float* __restrict__ W2, const float* __restrict__ b2,
    const float* __restrict__ W3, const float* __restrict__ b3,
    float* __restrict__ ws, float* __restrict__ out)
{
    __shared__ __align__(16) unsigned char smem[64 * 1024];  // 2 x 32 KB halves

    const int t    = threadIdx.x;
    const int lane = t & 63;
    const int w    = t >> 6;        // wave 0..7 -> q rows [w*32, w*32+32)
    const int lrow = lane & 15;     // fragment row index
    const int lq   = lane >> 4;     // quad: d = lq*8 + j
    const int bh   = blockIdx.x;
    const int qb   = blockIdx.y;

    // ---- Q loads first (vmcnt in-order: waiting on Q won't wait on K) ----
    const float SC = 0.18033688011112042592f;      // (1/sqrt(64)) * log2(e)
    const float* qrow = Q + ((size_t)bh * S + (size_t)qb * QBLK + w * QW + lrow) * DK;
    f32x8 qa = *(const f32x8*)(qrow + lq * 8);
    f32x8 qb_ = *(const f32x8*)(qrow + 32 + lq * 8);
    f32x8 qc = *(const f32x8*)(qrow + 16 * DK + lq * 8);
    f32x8 qd = *(const f32x8*)(qrow + 16 * DK + 32 + lq * 8);

    // ---- staging regs: 4 pairs = one 256-row phase (8 floats/thread/pair) --
    const float* Kb = K + (size_t)bh * S * DK;
    f32x4 s0a, s0b, s1a, s1b, s2a, s2b, s3a, s3b;

#define ISSUE(p) {                                                      \
        const float* _gp = Kb + (size_t)(p) * (KPH * DK) + (size_t)t * 8; \
        s0a = *(const f32x4*)(_gp);         s0b = *(const f32x4*)(_gp + 4);     \
        s1a = *(const f32x4*)(_gp + 4096);  s1b = *(const f32x4*)(_gp + 4100);  \
        s2a = *(const f32x4*)(_gp + 8192);  s2b = *(const f32x4*)(_gp + 8196);  \
        s3a = *(const f32x4*)(_gp + 12288); s3b = *(const f32x4*)(_gp + 12292); }

    // 16B-group n8 = I*512 + t of the phase: row = n8>>3, c8 = n8&7,
    // stored at byte r*128 + ((c8 ^ (r&7))<<4)  (T2 swizzle, r7: 0 conflicts)
#define WR1(dst, A, B, I) {                                             \
        const int _n8 = (I) * 512 + t;                                  \
        const int _r  = _n8 >> 3;                                       \
        const int _c8 = _n8 & 7;                                        \
        f32x8 _v = __builtin_shufflevector(A, B, 0, 1, 2, 3, 4, 5, 6, 7); \
        *(bf16x8*)((dst) + _r * 128 + (((_c8 ^ (_r & 7))) << 4)) =      \
            __builtin_convertvector(_v, bf16x8); }

#define WRITE(dst) { WR1(dst, s0a, s0b, 0) WR1(dst, s1a, s1b, 1)        \
                     WR1(dst, s2a, s2b, 2) WR1(dst, s3a, s3b, 3) }

#define PIPE_BAR() {                                                    \
        asm volatile("s_waitcnt lgkmcnt(0)" ::: "memory");              \
        __builtin_amdgcn_s_barrier();                                   \
        asm volatile("" ::: "memory"); }

    // ---- prologue: phase 0 staged, A-fragments built ----
    ISSUE(0);
    const bf16x8 a0_lo = __builtin_convertvector(qa * SC, bf16x8);
    const bf16x8 a0_hi = __builtin_convertvector(qb_ * SC, bf16x8);
    const bf16x8 a1_lo = __builtin_convertvector(qc * SC, bf16x8);
    const bf16x8 a1_hi = __builtin_convertvector(qd * SC, bf16x8);

    char* KsB = (char*)smem;
    WRITE(KsB);                         // waits phase-0 vmcnt only
    __syncthreads();                    // buf0 visible

    // per-row stats; chain u = f*4+i -> q-row w*32 + f*16 + lq*4 + i
    float m[8], Zs[8], Z2[8], sm[8];
#pragma unroll
    for (int u = 0; u < 8; ++u) { m[u] = -INFINITY; Zs[u] = 0.f; Z2[u] = 0.f; sm[u] = 0.f; }

    const int obase = lrow * 128 + ((lq ^ (lrow & 7)) << 4);

    for (int p = 0; p < NPH; ++p) {
        if (p + 1 < NPH) ISSUE(p + 1);  // in flight across the whole compute
        char* HB = KsB + (p & 1) * 32768;

#pragma unroll 4
        for (int j = 0; j < NST; ++j) {
            const int off = j * 2048 + obase;
            const bf16x8 b_lo = *(const bf16x8*)(HB + off);
            const bf16x8 b_hi = *(const bf16x8*)(HB + (off ^ 64));
            f32x4 ac0 = {0.f, 0.f, 0.f, 0.f};
            f32x4 ac1 = {0.f, 0.f, 0.f, 0.f};
            ac0 = __builtin_amdgcn_mfma_f32_16x16x32_bf16(a0_lo, b_lo, ac0, 0, 0, 0);
            ac0 = __builtin_amdgcn_mfma_f32_16x16x32_bf16(a0_hi, b_hi, ac0, 0, 0, 0);
            ac1 = __builtin_amdgcn_mfma_f32_16x16x32_bf16(a1_lo, b_lo, ac1, 0, 0, 0);
            ac1 = __builtin_amdgcn_mfma_f32_16x16x32_bf16(a1_hi, b_hi, ac1, 0, 0, 0);
#pragma unroll
            for (int i = 0; i < 4; ++i) {
                const float s0 = ac0[i], s1 = ac1[i];
                const float p0 = EXP2F(s0), p1 = EXP2F(s1);
                m[i]      = fmaxf(m[i], s0);      m[4 + i]  = fmaxf(m[4 + i], s1);
                Zs[i]    += p0;                   Zs[4 + i] += p1;
                Z2[i]     = fmaf(p0, p0, Z2[i]);
                Z2[4 + i] = fmaf(p1, p1, Z2[4 + i]);
                sm[i]    += s0;                   sm[4 + i] += s1;
            }
        }

        if (p + 1 < NPH) {
            WRITE(KsB + ((p + 1) & 1) * 32768);  // vmcnt wait: ~2.5k cyc old
            PIPE_BAR();                          // buf ready; vmcnt NOT drained
        }
    }
    __syncthreads();                    // all compute done; LDS reusable

    int*   lastF = (int*)smem;
    float* red   = (float*)(smem + 16);
    if (t < 3) red[t] = 0.0f;
    __syncthreads();

    // ---- reduce across the 16 column-lanes sharing each q-row ----
#pragma unroll
    for (int off = 1; off < 16; off <<= 1) {
#pragma unroll
        for (int u = 0; u < 8; ++u) {
            m[u]   = fmaxf(m[u], __shfl_xor(m[u], off, 64));
            Zs[u] += __shfl_xor(Zs[u], off, 64);
            Z2[u] += __shfl_xor(Z2[u], off, 64);
            sm[u] += __shfl_xor(sm[u], off, 64);
        }
    }
    if (lrow == 0) {
        const float LN2 = 0.69314718055994530942f;
        float psum = 0.f, pmax = 0.f, pvar = 0.f;
#pragma unroll
        for (int u = 0; u < 8; ++u) {
            psum += sm[u];
            pmax += m[u];
            const float iz = 1.0f / Zs[u];
            // var(probs, ddof=1) = (Z2/Z^2 - 1/n)/(n-1); scale-invariant
            pvar += (Z2[u] * iz * iz - (1.0f / 2048.0f)) * (1.0f / 2047.0f);
        }
        atomicAdd(&red[0], psum * LN2);          // back to natural-log domain
        atomicAdd(&red[1], pmax * LN2);
        atomicAdd(&red[2], pvar);
    }
    __syncthreads();
    if (t == 0) {
        atomicAdd(&ws[bh * 3 + 0], red[0]);
        atomicAdd(&ws[bh * 3 + 1], red[1]);
        atomicAdd(&ws[bh * 3 + 2], red[2]);
        __threadfence();
        const int old = atomicAdd((int*)(ws + 96), 1);
        *lastF = (old == NBLK - 1);
    }
    __syncthreads();
    if (!*lastF) return;

    // =========================== MLP head (last block) ======================
    float* H1    = (float*)(smem + 64);     // 32*65 floats
    float* featL = H1 + 32 * 65;            // 96 floats
    float* logtL = featL + 96;              // 32 floats

    if (t < 96)               featL[t] = atomicAdd(&ws[t], 0.0f); // coherent read
    if (t >= 96 && t < 128)   logtL[t - 96] = 0.0f;
    __syncthreads();

    if (t < 64) {
        const float w1a = W1[t], w1b = W1[64 + t], w1c = W1[128 + t], bb1 = b1[t];
        for (int b = 0; b < 32; ++b) {
            const float f0 = featL[b * 3 + 0] * (1.0f / ((float)S * (float)S));
            const float f1 = featL[b * 3 + 1] * (1.0f / (float)S);
            const float f2 = featL[b * 3 + 2] * (1.0f / (float)S);
            H1[b * 65 + t] = gelu_exact(f0 * w1a + f1 * w1b + f2 * w1c + bb1);
        }
    }
    __syncthreads();
    {
        // 512 threads: 16 threads per bh, 4 hidden-2 units each
        const int b = t >> 4, jb = (t & 15) * 4;
        float a0 = 0.f, a1 = 0.f, a2 = 0.f, a3 = 0.f;
        for (int k = 0; k < 64; ++k) {
            const float hk = H1[b * 65 + k];
            const float4 wa = *(const float4*)&W2[k * 64 + jb];
            a0 += hk * wa.x; a1 += hk * wa.y; a2 += hk * wa.z; a3 += hk * wa.w;
        }
        const float part = gelu_exact(a0 + b2[jb + 0]) * W3[jb + 0]
                         + gelu_exact(a1 + b2[jb + 1]) * W3[jb + 1]
                         + gelu_exact(a2 + b2[jb + 2]) * W3[jb + 2]
                         + gelu_exact(a3 + b2[jb + 3]) * W3[jb + 3];
        atomicAdd(&logtL[b], part);
    }
    __syncthreads();
    if (t < 32) {
        float lt = logtL[t] + b3[0];
        lt = fminf(fmaxf(lt, -2.3025850929940457f), 2.3025850929940457f);
        out[t] = expf(lt);
    }
}

// ---------------------------------------------------------------------------
extern "C" void kernel_launch(void* const* d_in, const int* in_sizes, int n_in,
                              void* d_out, int out_size, void* d_ws, size_t ws_size,
                              hipStream_t stream)
{
    const float* Q  = (const float*)d_in[0];
    const float* K  = (const float*)d_in[1];
    const float* W1 = (const float*)d_in[2];
    const float* b1 = (const float*)d_in[3];
    const float* W2 = (const float*)d_in[4];
    const float* b2 = (const float*)d_in[5];
    const float* W3 = (const float*)d_in[6];
    const float* b3 = (const float*)d_in[7];
    float* out = (float*)d_out;
    float* ws  = (float*)d_ws;

    // zero the 96 stat accumulators + the int block counter at ws[96]
    hipMemsetAsync(ws, 0, 512, stream);

    dim3 grid(NBH, NQB);   // bh fastest -> each bh's K pinned to one XCD L2
    fused_attn_stats_mlp<<<grid, NTHR, 0, stream>>>(Q, K, W1, b1, W2, b2, W3, b3, ws, out);
}